// Round 2
// baseline (475.637 us; speedup 1.0000x reference)
//
#include <hip/hip_runtime.h>

// Direct 3x3 conv, NCHW fp32. N=32, C_IN=3, H=W=224, C_OUT=64, stride 1, pad 1.
// v3: thread = 1x4 pixel strip x 8 c_out; ci-loop ROLLED (#pragma unroll 1).
//  - short body (~3 KB, I-cache resident) vs v1/v2's ~18 KB unrolled monster
//  - window regs live only within one ci iteration: 18 floats -> ~70 VGPR,
//    ~7 waves/SIMD, 2x total waves vs v2 (more stall hiding)
//  - float4 loads + float4 stores, weights/bias wave-uniform (scalar pipe)
// Accumulation order per output matches v1/v2 (bias, ci-major, r, dc):
// numerics identical, absmax unchanged.

#define N_IMG 32
#define C_IN 3
#define H_ 224
#define W_ 224
#define C_OUT 64
#define NPIX (H_ * W_)          // 50176
#define W4 (W_ / 4)             // 56 strips per row
#define STRIPS (NPIX / 4)       // 12544 = 49 * 256
#define COG 8                   // c_out per block (gridDim.y = 8)

__global__ __launch_bounds__(256, 5) void conv3x3_v3(
    const float* __restrict__ x,      // [N, C_IN, H, W]
    const float* __restrict__ wgt,    // [C_OUT, C_IN, 3, 3]
    const float* __restrict__ bias,   // [C_OUT]
    float* __restrict__ out)          // [N, C_OUT, H, W]
{
    const int s  = blockIdx.x * 256 + threadIdx.x;  // strip index within image
    const int cg = blockIdx.y * COG;                // first c_out of this group
    const int n  = blockIdx.z;
    const int h  = s / W4;
    const int w4 = (s - h * W4) * 4;                // leftmost pixel column

    // 8 couts x 4 pixels of accumulators, init with bias.
    float acc[COG][4];
#pragma unroll
    for (int co = 0; co < COG; ++co) {
        const float b = bias[cg + co];
        acc[co][0] = b; acc[co][1] = b; acc[co][2] = b; acc[co][3] = b;
    }

    const float* xn = x + (size_t)n * C_IN * NPIX;

#pragma unroll 1
    for (int ci = 0; ci < C_IN; ++ci) {
        // 3 rows x 6 cols window for this input channel; col 0 is w4-1.
        float win[3][6];
#pragma unroll
        for (int r = 0; r < 3; ++r) {
            const int hh = h + r - 1;
            const bool hok = (unsigned)hh < (unsigned)H_;
            const float* row = xn + ci * NPIX + hh * W_;
            if (hok) {
                const float4 m = *reinterpret_cast<const float4*>(row + w4);
                win[r][1] = m.x; win[r][2] = m.y;
                win[r][3] = m.z; win[r][4] = m.w;
                win[r][0] = (w4 > 0)      ? row[w4 - 1] : 0.0f;
                win[r][5] = (w4 + 4 < W_) ? row[w4 + 4] : 0.0f;
            } else {
#pragma unroll
                for (int c = 0; c < 6; ++c) win[r][c] = 0.0f;
            }
        }

        const float* wci = wgt + (size_t)cg * 27 + ci * 9;
#pragma unroll
        for (int co = 0; co < COG; ++co) {
            const float* wp = wci + (size_t)co * 27;
#pragma unroll
            for (int r = 0; r < 3; ++r)
#pragma unroll
                for (int dc = 0; dc < 3; ++dc) {
                    const float wv = wp[r * 3 + dc];
                    acc[co][0] += win[r][0 + dc] * wv;
                    acc[co][1] += win[r][1 + dc] * wv;
                    acc[co][2] += win[r][2 + dc] * wv;
                    acc[co][3] += win[r][3 + dc] * wv;
                }
        }
    }

    float* outp = out + ((size_t)n * C_OUT + cg) * NPIX + h * W_ + w4;
#pragma unroll
    for (int co = 0; co < COG; ++co) {
        float4 o;
        o.x = acc[co][0]; o.y = acc[co][1];
        o.z = acc[co][2]; o.w = acc[co][3];
        *reinterpret_cast<float4*>(outp + (size_t)co * NPIX) = o;
    }
}

extern "C" void kernel_launch(void* const* d_in, const int* in_sizes, int n_in,
                              void* d_out, int out_size, void* d_ws, size_t ws_size,
                              hipStream_t stream) {
    const float* x    = (const float*)d_in[0];
    const float* wgt  = (const float*)d_in[1];
    const float* bias = (const float*)d_in[2];
    float* out = (float*)d_out;

    dim3 grid(STRIPS / 256, C_OUT / COG, N_IMG);   // 49 x 8 x 32 blocks
    dim3 block(256);
    conv3x3_v3<<<grid, block, 0, stream>>>(x, wgt, bias, out);
}

// Round 3
// 452.747 us; speedup vs baseline: 1.0506x; 1.0506x over previous
//
#include <hip/hip_runtime.h>

// Direct 3x3 conv, NCHW fp32. N=32, C_IN=3, H=W=224, C_OUT=64, stride 1, pad 1.
// v4 = v1 (best-known, 457.7 us) with ONE change: nontemporal output stores.
// Output is write-once / never-read; `nt` avoids L2 allocation of the 411 MB
// write stream -> smaller dirty footprint, earlier writeback, L2 left for the
// input stencil. Clean single-variable A/B vs the v1 baseline.
// Accumulation order identical to v1 -> absmax unchanged.

#define N_IMG 32
#define C_IN 3
#define H_ 224
#define W_ 224
#define C_OUT 64
#define NPIX (H_ * W_)      // 50176 = 196 * 256
#define COB 16              // c_out per chunk

__global__ __launch_bounds__(256) void conv3x3_v4(
    const float* __restrict__ x,      // [N, C_IN, H, W]
    const float* __restrict__ wgt,    // [C_OUT, C_IN, 3, 3]
    const float* __restrict__ bias,   // [C_OUT]
    float* __restrict__ out)          // [N, C_OUT, H, W]
{
    const int p = blockIdx.x * 256 + threadIdx.x;   // pixel index within image
    const int n = blockIdx.y;
    const int h = p / W_;
    const int w = p - h * W_;

    // Load the 3x3x3 input window (zero padding at borders).
    float in_v[27];
    const float* xn = x + (size_t)n * C_IN * NPIX;
#pragma unroll
    for (int ci = 0; ci < 3; ++ci) {
#pragma unroll
        for (int dh = 0; dh < 3; ++dh) {
            const int hh = h + dh - 1;
            const bool hok = (unsigned)hh < (unsigned)H_;
#pragma unroll
            for (int dw = 0; dw < 3; ++dw) {
                const int ww = w + dw - 1;
                const bool ok = hok && ((unsigned)ww < (unsigned)W_);
                in_v[(ci * 3 + dh) * 3 + dw] =
                    ok ? xn[ci * NPIX + hh * W_ + ww] : 0.0f;
            }
        }
    }

    float* outp = out + (size_t)n * C_OUT * NPIX + p;
#pragma unroll
    for (int cb = 0; cb < C_OUT / COB; ++cb) {
        float acc[COB];
#pragma unroll
        for (int i = 0; i < COB; ++i) acc[i] = bias[cb * COB + i];
#pragma unroll
        for (int i = 0; i < COB; ++i) {
            const float* wp = wgt + (size_t)(cb * COB + i) * 27;
#pragma unroll
            for (int k = 0; k < 27; ++k) acc[i] += in_v[k] * wp[k];
        }
#pragma unroll
        for (int i = 0; i < COB; ++i)
            __builtin_nontemporal_store(acc[i],
                                        outp + (size_t)(cb * COB + i) * NPIX);
    }
}

extern "C" void kernel_launch(void* const* d_in, const int* in_sizes, int n_in,
                              void* d_out, int out_size, void* d_ws, size_t ws_size,
                              hipStream_t stream) {
    const float* x    = (const float*)d_in[0];
    const float* wgt  = (const float*)d_in[1];
    const float* bias = (const float*)d_in[2];
    float* out = (float*)d_out;

    dim3 grid(NPIX / 256, N_IMG);   // 196 x 32 blocks
    dim3 block(256);
    conv3x3_v4<<<grid, block, 0, stream>>>(x, wgt, bias, out);
}